// Round 6
// baseline (549.743 us; speedup 1.0000x reference)
//
#include <hip/hip_runtime.h>

// PWC-Net cost volume via banded MFMA GEMM. B=4, C=128, H=256, W=448, 81 shifts.
// out[b, di*9+dj, h, w] = (1/128) * sum_c feat1[b,c,h,w] * feat2[b,c,h+di-4,w+dj-4]
//
// Per (b,h,di): S[px][col] = sum_c F1[c,px] * F2[c,col]; needed band dj = col-px
// (col offset -4). Per 16-px tile, two 16x16x32 bf16 MFMAs (B col offsets -4, +4)
// cover dj 0..8 exactly once: tile0 <-> m+dj<=15, tile1 <-> m+dj>=16.
// Block = (b,h), 512 thr / 8 waves; W in 4 quarters of 112; C in 4 chunks of 32.
// LDS k-major atom layout (one ds_read_b128 per fragment), padded rows 113/121.
// Staging: lane=col, 8 coalesced dword loads over channels -> bf16 pack ->
// contiguous ds_write_b128. Epilogue via aliased LDS plane -> dwordx4 stores.

typedef __attribute__((ext_vector_type(8))) short bf16x8;
typedef __attribute__((ext_vector_type(4))) float f32x4;
typedef __attribute__((ext_vector_type(4))) int i32x4;

__device__ __forceinline__ unsigned short f2bf(float f) {
    unsigned u = __float_as_uint(f);
    return (unsigned short)((u + 0x7FFFu + ((u >> 16) & 1u)) >> 16);  // RNE
}

__global__ __launch_bounds__(512, 4) void cv_mfma(
    const float* __restrict__ feat1,
    const float* __restrict__ feat2,
    float* __restrict__ out)
{
    constexpr int C = 128, H = 256, W = 448;
    constexpr size_t HW = (size_t)H * W;
    constexpr int F2OFF = 7232;             // bytes: F1 region = 4*113*16
    __shared__ __align__(16) char smem[76928]; // F1 7232 + F2 9*4*121*16 = 69696

    const int tid  = threadIdx.x;
    const int wid  = tid >> 6;
    const int lane = tid & 63;
    const int g = lane >> 4, n = lane & 15;

    // XCD-contiguous (b,h) mapping (1024 = 8*128, bijective)
    const int lin = (blockIdx.x & 7) * 128 + (blockIdx.x >> 3);
    const int b = lin >> 8, h = lin & 255;

    const int oct = wid >> 1, batch = wid & 1;   // staging role of this wave
    const size_t bC = (size_t)b * C;

    // Job meta: j = wid + 8u -> (di, pt, tile); mb = B byte-offset minus lane
    // part, ma = A tile part. Wave-uniform (SGPR-friendly).
    int mb[16], ma[16];
#pragma unroll
    for (int u = 0; u < 16; ++u) {
        const int j = wid + 8 * u;
        const int dii = j / 14, r = j - dii * 14, pt = r >> 1, tl = r & 1;
        mb[u] = F2OFF + ((dii * 4) * 121 + pt * 16 + tl * 8) * 16;
        ma[u] = pt * 256;
    }
    const int lb = (g * 121 + n) * 16;   // B lane part
    const int la = (g * 113 + n) * 16;   // A lane part

    f32x4 acc[16];

    for (int q = 0; q < 4; ++q) {
        const int q0 = q * 112;
#pragma unroll
        for (int u = 0; u < 16; ++u) acc[u] = (f32x4){0.f, 0.f, 0.f, 0.f};

        for (int kc = 0; kc < 4; ++kc) {
            const int c0 = kc * 32 + oct * 8;
            __syncthreads();   // prior phase's LDS reads done before overwrite

            // ---- stage F1: atom (oct, px), k = oct*8+e
            {
                const int px = batch * 64 + lane;
                if (px < 112) {
                    const float* p = feat1 + (bC + c0) * HW + (size_t)h * W + (q0 + px);
                    float v[8];
#pragma unroll
                    for (int e = 0; e < 8; ++e) v[e] = p[e * HW];
                    i32x4 wv;
#pragma unroll
                    for (int d2 = 0; d2 < 4; ++d2)
                        wv[d2] = (int)f2bf(v[2 * d2]) | ((int)f2bf(v[2 * d2 + 1]) << 16);
                    *(i32x4*)(smem + (oct * 113 + px) * 16) = wv;
                }
            }
            // ---- stage F2: atoms (di, oct, t), col_g = q0-4+t
            for (int di = 0; di < 9; ++di) {
                const int t  = batch * 64 + lane;
                const int cg = q0 - 4 + t;
                const int hr = h + di - 4;
                const bool ok = (t < 120) && (cg >= 0) && (cg < W) && (hr >= 0) && (hr < H);
                const float* p = feat2 + (bC + c0) * HW
                               + (size_t)(ok ? hr : 0) * W + (ok ? cg : 0);
                float v[8];
#pragma unroll
                for (int e = 0; e < 8; ++e) v[e] = ok ? p[e * HW] : 0.f;
                if (t < 120) {
                    i32x4 wv;
#pragma unroll
                    for (int d2 = 0; d2 < 4; ++d2)
                        wv[d2] = (int)f2bf(v[2 * d2]) | ((int)f2bf(v[2 * d2 + 1]) << 16);
                    *(i32x4*)(smem + F2OFF + ((di * 4 + oct) * 121 + t) * 16) = wv;
                }
            }
            __syncthreads();

            // ---- MFMA: 16 jobs per wave
#pragma unroll
            for (int u = 0; u < 16; ++u) {
                if (wid + 8 * u < 126) {
                    const bf16x8 af  = *(const bf16x8*)(smem + ma[u] + la);
                    const bf16x8 bfr = *(const bf16x8*)(smem + mb[u] + lb);
                    acc[u] = __builtin_amdgcn_mfma_f32_16x16x32_bf16(af, bfr, acc[u], 0, 0, 0);
                }
            }
        }

        // ---- epilogue: frags -> LDS out plane (aliases stage region)
        __syncthreads();
        float* lo = (float*)smem;   // 81*112*4 = 36288 B
#pragma unroll
        for (int u = 0; u < 16; ++u) {
            const int j = wid + 8 * u;
            if (j < 126) {
                const int dii = j / 14, r = j - dii * 14, pt = r >> 1, tl = r & 1;
#pragma unroll
                for (int reg = 0; reg < 4; ++reg) {
                    const int m = g * 4 + reg;      // C row (px offset in tile)
                    const int d = n - m;            // n = C col (window col)
                    const float val = acc[u][reg] * (1.0f / 128.0f);
                    if (tl == 0) {
                        if (d >= 0 && d <= 8)
                            lo[(dii * 9 + d) * 112 + pt * 16 + m] = val;
                    } else {
                        if (n >= 8 && d <= 0)
                            lo[(dii * 9 + d + 8) * 112 + pt * 16 + m] = val;
                    }
                }
            }
        }
        __syncthreads();

        // ---- drain: 81 x 112 floats, coalesced dwordx4 stores
        for (int v = tid; v < 81 * 28; v += 512) {
            const int s = v / 28, cq = v - s * 28;
            const f32x4 val = *(const f32x4*)(lo + s * 112 + cq * 4);
            *(f32x4*)(out + ((size_t)(b * 81 + s) * H + h) * W + (q0 + cq * 4)) = val;
        }
        // next quarter's top __syncthreads() protects lo reads vs re-staging
    }
}

extern "C" void kernel_launch(void* const* d_in, const int* in_sizes, int n_in,
                              void* d_out, int out_size, void* d_ws, size_t ws_size,
                              hipStream_t stream) {
    const float* feat1 = (const float*)d_in[0];
    const float* feat2 = (const float*)d_in[1];
    float* out = (float*)d_out;
    cv_mfma<<<dim3(1024), dim3(512), 0, stream>>>(feat1, feat2, out);
}

// Round 7
// 386.300 us; speedup vs baseline: 1.4231x; 1.4231x over previous
//
#include <hip/hip_runtime.h>

// PWC-Net cost volume, fp32. B=4, C=128, H=256, W=448, 81 shifts.
// out[b, di*9+dj, h, w] = (1/128) * sum_c feat1[b,c,h,w] * feat2[b,c,h+di-4,w+dj-4]
//
// Block = (b,h), 512 thr / 8 waves. Lane item it = tid: di = it/56,
// px0 = (it%56)*8 (504 real). feat2 rows h-4..h+4 in LDS, 1 ch/chunk,
// double-buffered. LDS row = 114 atoms of 16B: slot 0 / 113 = zero halo
// (zeroed once, never re-staged), slots 1..112 = cols 0..447, atom a at slot
// 1 + half*56 + swz(a - half*56), swz(x) = x ^ ((x>>3)&7) (involution; image
// of [0,56) stays in [0,56)). Staged by 18 56-lane global_load_lds(16B) with
// pre-swizzled GLOBAL source (LDS dest linear). OOB rows: stage skipped ->
// startup zeros persist.
//
// Schedule (drain-old, single barrier, regs <= 128 so 2 blocks/CU):
//   top: s_waitcnt vmcnt(0)   <- drains stage(t)/feat1(t), issued LAST iter
//        s_barrier            <- publishes stage(t); prior reads of buf^1 done
//   issue stage(t+1) + feat1(t+1)  (in flight across compute(t))
//   ds_read window + 72 FMA

typedef __attribute__((ext_vector_type(4))) float f32x4;

#define GLAS(p) ((const __attribute__((address_space(1))) unsigned int*)(p))
#define LDAS(p) ((__attribute__((address_space(3))) unsigned int*)(p))

__global__ __launch_bounds__(512, 4) void cv_kernel(
    const float* __restrict__ feat1,
    const float* __restrict__ feat2,
    float* __restrict__ out)
{
    constexpr int C = 128, H = 256, W = 448;
    constexpr size_t HW = (size_t)H * W;
    constexpr int ROWB = 114 * 16;    // 1824 B per LDS row
    constexpr int BUFB = 9 * ROWB;    // 16416 B per buffer
    __shared__ __align__(16) char f2s[2 * BUFB];   // 32832 B

    const int tid  = threadIdx.x;
    const int wid  = tid >> 6;
    const int lane = tid & 63;

    // XCD-contiguous (b,h): consecutive lin = consecutive h on one XCD.
    const int lin = (blockIdx.x & 7) * 128 + (blockIdx.x >> 3);
    const int b = lin >> 8, h = lin & 255;

    const int it  = (tid < 504) ? tid : 503;
    const int di  = it / 56;
    const int m   = it - di * 56;
    const int px0 = m << 3;

    // Zero all LDS once: halo slots + OOB rows stay zero (never re-staged).
    for (int i = tid; i < (2 * BUFB) / 16; i += 512)
        *(f32x4*)(f2s + i * 16) = (f32x4){0.f, 0.f, 0.f, 0.f};

    const int swl = lane ^ ((lane >> 3) & 7);
    const size_t bbase = (size_t)b * C * H;

    // Staging descriptors: wave w -> issues j = w, w+8, (16+w if w<2).
    // issue j: row r=j>>1, half cc=j&1. Lane l (<56) loads atom cc*56+swz(l)
    // (cols 4*that..+3) into dest slot 1+cc*56+l.
    const int nIss = (wid < 2) ? 3 : 2;
    unsigned svo[3]; int sdst[3]; bool srv[3];
#pragma unroll
    for (int k = 0; k < 3; ++k) {
        const int j  = (k < 2) ? (wid + 8 * k) : (16 + wid);
        const int r  = j >> 1, cc = j & 1;
        const int hr = h + r - 4;
        srv[k]  = (hr >= 0) && (hr < H);
        svo[k]  = (unsigned)((bbase + (size_t)(srv[k] ? hr : 0)) * W)
                + (unsigned)(cc * 224 + swl * 4);          // float index
        sdst[k] = r * ROWB + 16 + cc * 896;
    }

    // Window read offsets: atoms a = 2m-1 .. 2m+2 (cols 8m-4 .. 8m+11).
    int lofs[4];
#pragma unroll
    for (int k = 0; k < 4; ++k) {
        const int a = 2 * m - 1 + k;
        int slot;
        if (a < 0)        slot = 0;        // left halo (zero)
        else if (a > 111) slot = 113;      // right halo (zero)
        else {
            const int hf = (a >= 56) ? 1 : 0;
            const int al = a - hf * 56;
            slot = 1 + hf * 56 + (al ^ ((al >> 3) & 7));
        }
        lofs[k] = di * ROWB + slot * 16;
    }

    unsigned f1o = (unsigned)((bbase + (size_t)h) * W) + (unsigned)px0;

    float acc[9][8];
#pragma unroll
    for (int j = 0; j < 9; ++j)
#pragma unroll
        for (int p = 0; p < 8; ++p) acc[j][p] = 0.0f;

    __syncthreads();   // LDS zeros visible before first stage reads/writes

    auto stage = [&](int dstofs) {
#pragma unroll
        for (int k = 0; k < 3; ++k) {
            if (k < nIss && srv[k]) {                  // wave-uniform
                if (lane < 56)
                    __builtin_amdgcn_global_load_lds(GLAS(feat2 + svo[k]),
                        LDAS(f2s + dstofs + sdst[k]), 16, 0, 0);
                svo[k] += (unsigned)HW;
            }
        }
    };

    // Prologue: stage(0) + feat1(0). (Only these are drained just-issued.)
    stage(0);
    f32x4 a0 = *(const f32x4*)(feat1 + f1o);
    f32x4 a1 = *(const f32x4*)(feat1 + f1o + 4);
    f1o += (unsigned)HW;

    auto body = [&](int t, int bufofs) {
        asm volatile("s_waitcnt vmcnt(0)" ::: "memory");   // drain OLD loads
        __builtin_amdgcn_s_barrier();                      // publish stage(t)
        __builtin_amdgcn_sched_barrier(0);                 // nothing crosses

        f32x4 n0 = a0, n1 = a1;
        if (t + 1 < C) {
            stage(bufofs ^ BUFB);                          // in flight over compute
            n0 = *(const f32x4*)(feat1 + f1o);
            n1 = *(const f32x4*)(feat1 + f1o + 4);
            f1o += (unsigned)HW;
        }

        const char* lb = f2s + bufofs;
        const f32x4 w0 = *(const f32x4*)(lb + lofs[0]);
        const f32x4 w1 = *(const f32x4*)(lb + lofs[1]);
        const f32x4 w2 = *(const f32x4*)(lb + lofs[2]);
        const f32x4 w3 = *(const f32x4*)(lb + lofs[3]);

        const float a[8]  = {a0.x, a0.y, a0.z, a0.w, a1.x, a1.y, a1.z, a1.w};
        const float w[16] = {w0.x, w0.y, w0.z, w0.w, w1.x, w1.y, w1.z, w1.w,
                             w2.x, w2.y, w2.z, w2.w, w3.x, w3.y, w3.z, w3.w};
#pragma unroll
        for (int dj = 0; dj < 9; ++dj)
#pragma unroll
            for (int p = 0; p < 8; ++p)
                acc[dj][p] = fmaf(a[p], w[dj + p], acc[dj][p]);

        a0 = n0; a1 = n1;
    };

    for (int t = 0; t < C; t += 2) {
        body(t, 0);
        body(t + 1, BUFB);
    }

    if (tid < 504) {
        const float s = 1.0f / 128.0f;
        float* ob = out + (((size_t)(b * 81 + di * 9)) * H + h) * W + px0;
#pragma unroll
        for (int dj = 0; dj < 9; ++dj) {
            f32x4 o0, o1;
            o0.x = acc[dj][0] * s; o0.y = acc[dj][1] * s;
            o0.z = acc[dj][2] * s; o0.w = acc[dj][3] * s;
            o1.x = acc[dj][4] * s; o1.y = acc[dj][5] * s;
            o1.z = acc[dj][6] * s; o1.w = acc[dj][7] * s;
            float* op = ob + (size_t)dj * HW;
            *(f32x4*)(op)     = o0;
            *(f32x4*)(op + 4) = o1;
        }
    }
}

extern "C" void kernel_launch(void* const* d_in, const int* in_sizes, int n_in,
                              void* d_out, int out_size, void* d_ws, size_t ws_size,
                              hipStream_t stream) {
    const float* feat1 = (const float*)d_in[0];
    const float* feat2 = (const float*)d_in[1];
    float* out = (float*)d_out;
    cv_kernel<<<dim3(1024), dim3(512), 0, stream>>>(feat1, feat2, out);
}